// Round 1
// 787.612 us; speedup vs baseline: 1.1555x; 1.1555x over previous
//
#include <hip/hip_runtime.h>
#include <hip/hip_bf16.h>

// GCN via CSR counting-sort. Round-4 changes vs round-3:
//  - hist_kernel records each edge's per-(XCD,node) local rank (the atomic's
//    return value) packed with the XCD id -> rank[E] (sequential write)
//  - scanA converts cnt8 in place to per-node exclusive prefixes over XCDs
//  - scatter_kernel computes pos = row_start[d] + xcd_prefix + local_rank
//    with NO atomics (round-3's device-scope atomicAdd(&cursor[dst]) was a
//    memory-side RMW latency chain: 252us, VALUBusy 0.4%)
//  - rank[E] aliases the t/h1 region (dead before gemm1 writes t), so the
//    workspace footprint does not grow

#define D_IN 512
#define D_HID 16
#define D_OUT 64
#define NB 256   // scan blocks
#define BT 256   // threads per block

__device__ __forceinline__ int xcc_id() {
    int id;
    asm volatile("s_getreg_b32 %0, hwreg(HW_REG_XCC_ID)" : "=s"(id));
    return id & 7;
}

// cnt8[x][d]++ with XCD-local L2 atomics; record packed (xcd, local_rank).
__global__ void hist_kernel(const int* __restrict__ dst, int* __restrict__ cnt8,
                            int* __restrict__ rank, int N, int E) {
    int e = blockIdx.x * blockDim.x + threadIdx.x;
    if (e >= E) return;
    int x = xcc_id();
    int r = __hip_atomic_fetch_add(&cnt8[(size_t)x * N + dst[e]], 1,
                                   __ATOMIC_RELAXED, __HIP_MEMORY_SCOPE_WORKGROUP);
    rank[e] = (x << 27) | r;   // r < E = 3.2M < 2^27
}

// In place: cnt8[x][n] <- sum_{x'<x} cnt8[x'][n] (exclusive prefix over XCDs).
// cnt_tot[n] = total; bsum[b] = sum over block's node chunk.
__global__ __launch_bounds__(BT) void scanA_kernel(int* __restrict__ cnt8,
                                                   int* __restrict__ cnt_tot,
                                                   int* __restrict__ bsum, int N) {
    __shared__ int red[BT / 64];
    int b = blockIdx.x;
    int chunk = (N + NB - 1) / NB;
    int beg = b * chunk, end = min(beg + chunk, N);
    int local = 0;
    for (int n = beg + threadIdx.x; n < end; n += BT) {
        int p = 0;
#pragma unroll
        for (int x = 0; x < 8; ++x) {
            int c = cnt8[(size_t)x * N + n];
            cnt8[(size_t)x * N + n] = p;
            p += c;
        }
        cnt_tot[n] = p;
        local += p;
    }
#pragma unroll
    for (int off = 32; off; off >>= 1) local += __shfl_down(local, off, 64);
    if ((threadIdx.x & 63) == 0) red[threadIdx.x >> 6] = local;
    __syncthreads();
    if (threadIdx.x == 0) {
        int s = 0;
#pragma unroll
        for (int i = 0; i < BT / 64; ++i) s += red[i];
        bsum[b] = s;
    }
}

// exclusive scan of bsum[NB] -> bbase[NB]
__global__ __launch_bounds__(NB) void scanB_kernel(const int* __restrict__ bsum,
                                                   int* __restrict__ bbase) {
    __shared__ int s[NB];
    int t = threadIdx.x;
    int orig = bsum[t];
    s[t] = orig;
    __syncthreads();
    for (int off = 1; off < NB; off <<= 1) {
        int v = (t >= off) ? s[t - off] : 0;
        __syncthreads();
        s[t] += v;
        __syncthreads();
    }
    bbase[t] = s[t] - orig;
}

// row_start[n] from cnt_tot and bbase.
__global__ __launch_bounds__(BT) void scanC_kernel(const int* __restrict__ cnt_tot,
                                                   const int* __restrict__ bbase,
                                                   int* __restrict__ row_start, int N, int E) {
    __shared__ int ex[BT];
    int b = blockIdx.x;
    int chunk = (N + NB - 1) / NB;
    int per = (chunk + BT - 1) / BT;
    int beg = b * chunk, end = min(beg + chunk, N);
    int tbeg = min(beg + threadIdx.x * per, end);
    int tend = min(tbeg + per, end);
    int s = 0;
    for (int n = tbeg; n < tend; ++n) s += cnt_tot[n];
    int orig = s;
    int t = threadIdx.x;
    ex[t] = s;
    __syncthreads();
    for (int off = 1; off < BT; off <<= 1) {
        int v = (t >= off) ? ex[t - off] : 0;
        __syncthreads();
        ex[t] += v;
        __syncthreads();
    }
    int running = bbase[b] + ex[t] - orig;
    for (int n = tbeg; n < tend; ++n) {
        row_start[n] = running;
        running += cnt_tot[n];
    }
    if (b == 0 && t == 0) row_start[N] = E;
}

// Atomic-free scatter: pos = row_start[d] + xcd_prefix[x][d] + local_rank.
// row_start (400KB) and off8 (3.2MB) are read-only gathers -> L2-resident.
__global__ void scatter_kernel(const int* __restrict__ src, const int* __restrict__ dst,
                               const float* __restrict__ w, const int* __restrict__ rank,
                               const int* __restrict__ row_start, const int* __restrict__ off8,
                               float2* __restrict__ sorted, int N, int E) {
    int e = blockIdx.x * blockDim.x + threadIdx.x;
    if (e >= E) return;
    int d = dst[e];
    int pk = rank[e];
    int x = pk >> 27;
    int r = pk & ((1 << 27) - 1);
    int pos = row_start[d] + off8[(size_t)x * N + d] + r;
    sorted[pos] = make_float2(__int_as_float(src[e]), w[e]);
}

// dinv[n] = rsqrt(1 + sum of w over CSR row). One wave per node.
__global__ __launch_bounds__(256) void dinv_kernel(const float2* __restrict__ sorted,
                                                   const int* __restrict__ row_start,
                                                   float* __restrict__ dinv, int N) {
    int node = blockIdx.x * 4 + (threadIdx.x >> 6);
    if (node >= N) return;
    int lane = threadIdx.x & 63;
    int beg = row_start[node], end = row_start[node + 1];
    float s = 0.0f;
    for (int e = beg + lane; e < end; e += 64) s += sorted[e].y;
#pragma unroll
    for (int off = 32; off; off >>= 1) s += __shfl_xor(s, off, 64);
    if (lane == 0) dinv[node] = __frsqrt_rn(1.0f + s);
}

// t[N][16] = x[N][512] @ W1[512][16]; 16 lanes/row, each owns 8 float4 k-slices.
__global__ __launch_bounds__(256) void gemm1_kernel(const float* __restrict__ x,
                                                    const float* __restrict__ W1,
                                                    float* __restrict__ t, int N) {
    __shared__ float w1t[16 * 520];
    for (int idx = threadIdx.x; idx < D_IN * D_HID; idx += 256) {
        int k = idx >> 4, j = idx & 15;
        w1t[j * 520 + k] = W1[idx];
    }
    __syncthreads();

    const int wave = threadIdx.x >> 6;
    const int lane = threadIdx.x & 63;
    const int g = lane >> 4;
    const int s = lane & 15;

    for (int base = blockIdx.x * 16; base < N; base += gridDim.x * 16) {
        int row = base + wave * 4 + g;
        if (row < N) {
            const float4* xr = (const float4*)(x + (size_t)row * D_IN);
            float4 xv[8];
#pragma unroll
            for (int i = 0; i < 8; ++i) xv[i] = xr[s + 16 * i];
            float acc[16];
#pragma unroll
            for (int j = 0; j < 16; ++j) acc[j] = 0.0f;
#pragma unroll
            for (int i = 0; i < 8; ++i) {
                int kb = 4 * s + 64 * i;
#pragma unroll
                for (int j = 0; j < 16; ++j) {
                    const float4 wv = *(const float4*)&w1t[j * 520 + kb];
                    acc[j] += xv[i].x * wv.x + xv[i].y * wv.y + xv[i].z * wv.z + xv[i].w * wv.w;
                }
            }
#pragma unroll
            for (int j = 0; j < 16; ++j) {
#pragma unroll
                for (int m = 1; m < 16; m <<= 1) acc[j] += __shfl_xor(acc[j], m, 64);
            }
            float v = acc[0];
#pragma unroll
            for (int j = 1; j < 16; ++j) v = (s == j) ? acc[j] : v;
            t[(size_t)row * 16 + s] = v;
        }
    }
}

// One wave per node, lane = k*16 + j (k = edge slice, j = feature dim).
// acc_j = sum over row of dinv[s]*w*feat[s][j]; out = dinv[n]*acc + dinv[n]^2*selfv.
template <int LAYER>
__global__ __launch_bounds__(256) void agg_kernel(const float2* __restrict__ sorted,
                                                  const int* __restrict__ row_start,
                                                  const float* __restrict__ feat,
                                                  const float* __restrict__ selfv,
                                                  const float* __restrict__ dinv,
                                                  const float* __restrict__ b1,
                                                  float* __restrict__ outp, int N) {
    int node = blockIdx.x * 4 + (threadIdx.x >> 6);
    if (node >= N) return;
    int lane = threadIdx.x & 63;
    int j = lane & 15, k = lane >> 4;
    int beg = row_start[node], end = row_start[node + 1];
    float acc = 0.0f;
    for (int e = beg + k; e < end; e += 4) {
        float2 p = sorted[e];
        int s = __float_as_int(p.x);
        acc += dinv[s] * p.y * feat[(size_t)s * 16 + j];
    }
    acc += __shfl_xor(acc, 16, 64);
    acc += __shfl_xor(acc, 32, 64);
    float dn = dinv[node];
    float sv = selfv[(size_t)node * 16 + j];
    float r = dn * acc + dn * dn * sv;
    if (LAYER == 1) r = fmaxf(r + b1[j], 0.0f);
    if (k == 0) outp[(size_t)node * 16 + j] = r;
}

// out[node][c] = log_softmax( v[node] @ W2 + b2 ); one wave per node.
__global__ __launch_bounds__(256) void out_kernel(const float* __restrict__ v,
                                                  const float* __restrict__ W2,
                                                  const float* __restrict__ b2,
                                                  float* __restrict__ out, int N) {
    __shared__ float w2s[16 * 64];
    __shared__ float b2s[64];
    for (int idx = threadIdx.x; idx < 16 * 64; idx += 256) w2s[idx] = W2[idx];
    if (threadIdx.x < 64) b2s[threadIdx.x] = b2[threadIdx.x];
    __syncthreads();

    const int wave = threadIdx.x >> 6;
    const int lane = threadIdx.x & 63;

    for (int node = blockIdx.x * 4 + wave; node < N; node += gridDim.x * 4) {
        const float4* v4 = (const float4*)(v + (size_t)node * 16);
        float z = b2s[lane];
#pragma unroll
        for (int q = 0; q < 4; ++q) {
            float4 a = v4[q];
            z += a.x * w2s[(4 * q + 0) * 64 + lane];
            z += a.y * w2s[(4 * q + 1) * 64 + lane];
            z += a.z * w2s[(4 * q + 2) * 64 + lane];
            z += a.w * w2s[(4 * q + 3) * 64 + lane];
        }
        float m = z;
#pragma unroll
        for (int off = 32; off; off >>= 1) m = fmaxf(m, __shfl_xor(m, off, 64));
        float ez = __expf(z - m);
        float ssum = ez;
#pragma unroll
        for (int off = 32; off; off >>= 1) ssum += __shfl_xor(ssum, off, 64);
        out[(size_t)node * 64 + lane] = z - m - __logf(ssum);
    }
}

extern "C" void kernel_launch(void* const* d_in, const int* in_sizes, int n_in,
                              void* d_out, int out_size, void* d_ws, size_t ws_size,
                              hipStream_t stream) {
    const float* x  = (const float*)d_in[0];
    const int*   ei = (const int*)d_in[1];
    const float* ew = (const float*)d_in[2];
    const float* W1 = (const float*)d_in[3];
    const float* b1 = (const float*)d_in[4];
    const float* W2 = (const float*)d_in[5];
    const float* b2 = (const float*)d_in[6];
    float* out = (float*)d_out;

    const int N = in_sizes[0] / D_IN;
    const int E = in_sizes[2];
    const int* srcI = ei;
    const int* dstI = ei + E;

    // ws layout (float units):
    // dinv[N] cnt_tot[N] row_start[N+2] bsum[256] bbase[256]
    // cnt8[8N] t[16N] h1[16N] sorted[2E]
    float* ws = (float*)d_ws;
    float* dinv      = ws;
    int*   cnt_tot   = (int*)(ws + (size_t)N);
    int*   row_start = (int*)(ws + 2 * (size_t)N);
    int*   bsum      = (int*)(ws + 3 * (size_t)N + 2);
    int*   bbase     = (int*)(ws + 3 * (size_t)N + 258);
    int*   cnt8      = (int*)(ws + 3 * (size_t)N + 514);
    float* t         = ws + 11 * (size_t)N + 514;
    float* h1        = ws + 27 * (size_t)N + 514;
    float2* sorted   = (float2*)(ws + 43 * (size_t)N + 514);
    float* v = t;  // reuse t as layer-2 aggregate

    // rank[E] aliases t/h1 (32N floats >= E ints here): rank is written by
    // hist, consumed by scatter, and dead before gemm1 writes t.
    int* rank = ((size_t)E <= 32 * (size_t)N)
                    ? (int*)t
                    : (int*)(ws + 43 * (size_t)N + 514 + 2 * (size_t)E);

    hipMemsetAsync(cnt8, 0, (size_t)8 * N * sizeof(int), stream);

    hist_kernel<<<(E + 255) / 256, 256, 0, stream>>>(dstI, cnt8, rank, N, E);
    scanA_kernel<<<NB, BT, 0, stream>>>(cnt8, cnt_tot, bsum, N);
    scanB_kernel<<<1, NB, 0, stream>>>(bsum, bbase);
    scanC_kernel<<<NB, BT, 0, stream>>>(cnt_tot, bbase, row_start, N, E);
    scatter_kernel<<<(E + 255) / 256, 256, 0, stream>>>(srcI, dstI, ew, rank,
                                                        row_start, cnt8, sorted, N, E);
    dinv_kernel<<<(N + 3) / 4, 256, 0, stream>>>(sorted, row_start, dinv, N);

    gemm1_kernel<<<1024, 256, 0, stream>>>(x, W1, t, N);

    agg_kernel<1><<<(N + 3) / 4, 256, 0, stream>>>(sorted, row_start, t, t, dinv, b1, h1, N);
    agg_kernel<2><<<(N + 3) / 4, 256, 0, stream>>>(sorted, row_start, h1, h1, dinv, b1, v, N);

    out_kernel<<<2048, 256, 0, stream>>>(v, W2, b2, out, N);
}